// Round 12
// baseline (250.714 us; speedup 1.0000x reference)
//
#include <hip/hip_runtime.h>
#include <math.h>

#define Cch 128
#define Hh 128
#define Ww 128
#define HW (Hh * Ww)

typedef __attribute__((ext_vector_type(8))) short short8;
typedef __attribute__((ext_vector_type(4))) float float4v;
typedef __attribute__((ext_vector_type(2))) float float2v;
typedef __attribute__((ext_vector_type(4))) unsigned int uint4v;

__device__ __forceinline__ unsigned short f2bf(float f) {
    unsigned u = __float_as_uint(f);
    return (unsigned short)((u + 0x8000u) >> 16);
}
__device__ __forceinline__ float2v up2(unsigned u) {
    return (float2v){__uint_as_float(u << 16), __uint_as_float(u & 0xffff0000u)};
}
__device__ __forceinline__ unsigned packbf2(float lo, float hi) {
    unsigned a = __float_as_uint(lo), b = __float_as_uint(hi);
    return ((a + 0x8000u) >> 16) | ((b + 0x8000u) & 0xffff0000u);
}

// ---- K1: x [B][C][H][W] fp32 -> xt [B][HW][C] bf16 ---------------------------
__global__ __launch_bounds__(256) void transpose_x_bf16(const float* __restrict__ x,
                                                        unsigned short* __restrict__ xt) {
    __shared__ float tile[32][33];
    int b  = blockIdx.z;
    int c0 = blockIdx.y * 32;
    int p0 = blockIdx.x * 32;
    int tx = threadIdx.x, ty = threadIdx.y;
    const float* xb = x + (size_t)b * Cch * HW;
    unsigned short* xtb = xt + (size_t)b * HW * Cch;
    #pragma unroll
    for (int i = 0; i < 32; i += 8)
        tile[ty + i][tx] = xb[(size_t)(c0 + ty + i) * HW + p0 + tx];
    __syncthreads();
    #pragma unroll
    for (int i = 0; i < 32; i += 8)
        xtb[(size_t)(p0 + ty + i) * Cch + c0 + tx] = f2bf(tile[tx][ty + i]);
}

// ---- K2: build B-fragment-linear weight layouts (bf16) -----------------------
#define NFB (9 * 4 * 8 * 64 * 8)
#define NFO (9 * 4 * 2 * 64 * 8)
__global__ __launch_bounds__(256) void build_frags(const float* __restrict__ w_def,
                                                   const float* __restrict__ w_off,
                                                   unsigned short* __restrict__ wfB,
                                                   unsigned short* __restrict__ wfO) {
    int idx = blockIdx.x * 256 + threadIdx.x;
    if (idx < NFB) {
        int j = idx & 7, lane = (idx >> 3) & 63, t = (idx >> 9) & 7;
        int q = (idx >> 12) & 3, k = idx >> 14;
        int c = 32 * q + 8 * (lane >> 4) + j;
        int o = 16 * t + (lane & 15);
        wfB[idx] = f2bf(w_def[(size_t)(o * Cch + c) * 9 + k]);
    } else if (idx < NFB + NFO) {
        int i2 = idx - NFB;
        int j = i2 & 7, lane = (i2 >> 3) & 63, t = (i2 >> 9) & 1;
        int q = (i2 >> 10) & 3, k = i2 >> 12;
        int c = 32 * q + 8 * (lane >> 4) + j;
        int o = 16 * t + (lane & 15);
        wfO[i2] = (o < 18) ? f2bf(w_off[(size_t)(o * Cch + c) * 9 + k]) : (unsigned short)0;
    }
}

// ---- block -> (b, h, w0): XCD-pinned (blk%8 = XCD, 2 XCDs per image) ---------
__device__ __forceinline__ void blk_map(int blk, int& b, int& h, int& w0) {
    int xcd = blk & 7;
    b = xcd >> 1;
    int seg = ((xcd & 1) << 8) | (blk >> 3);  // 0..511
    h  = seg >> 2;
    w0 = (seg & 3) << 5;
}

// ---- K3: fully fused, bf16, runtime tap loops (I-cache friendly) -------------
__global__ __launch_bounds__(128, 2) void fused_rt(const unsigned short* __restrict__ xt,
                                                   const unsigned short* __restrict__ wfB,
                                                   const unsigned short* __restrict__ wfO,
                                                   const float* __restrict__ b_off,
                                                   const float* __restrict__ b_def,
                                                   const float* __restrict__ w_attn,
                                                   const float* __restrict__ b_attn,
                                                   float* __restrict__ out) {
    __shared__ float4v red[2 * 8 * 64];   // 16 KiB
    __shared__ float   offs[32 * 18];     // 2.3 KiB
    int b, h, w0;
    blk_map(blockIdx.x, b, h, w0);
    int tid  = threadIdx.x;
    int wave = tid >> 6;
    int lane = tid & 63;
    int col  = lane & 15;
    int s    = lane >> 4;
    int cbase = 64 * wave;
    int cofs  = cbase + 8 * s;

    const unsigned short* xtb = xt + (size_t)b * HW * Cch;

    // ================= Phase 1: offset conv (runtime k-loop) ==================
    {
        float4v acc2[2][2];
        #pragma unroll
        for (int pt = 0; pt < 2; ++pt)
            #pragma unroll
            for (int t = 0; t < 2; ++t) {
                int o = 16 * t + col;
                float bv = (wave == 0 && o < 18) ? b_off[o] : 0.0f;
                acc2[pt][t] = (float4v){bv, bv, bv, bv};
            }

        #pragma unroll 1
        for (int k = 0; k < 9; ++k) {
            int ky = (k * 11) >> 5;          // k/3 for k in [0,9)
            int dxk = k - 3 * ky - 1;
            int y = h + ky - 1;
            bool vy = (y >= 0) && (y < Hh);
            int yc = min(max(y, 0), Hh - 1);
            int  ofs[2];
            bool val[2];
            #pragma unroll
            for (int pt = 0; pt < 2; ++pt) {
                int px = w0 + 16 * pt + col;
                int xs = px + dxk;
                val[pt] = vy && (xs >= 0) && (xs < Ww);
                int xc  = min(max(xs, 0), Ww - 1);
                ofs[pt] = (yc * Ww + xc) * Cch + cofs;
            }
            #pragma unroll
            for (int qq = 0; qq < 2; ++qq) {
                int q = 2 * wave + qq;
                short8 aa[2];
                #pragma unroll
                for (int pt = 0; pt < 2; ++pt) {
                    short8 av = *(const short8*)(xtb + ofs[pt] + 32 * qq);
                    if (!val[pt]) av = (short8)0;
                    aa[pt] = av;
                }
                #pragma unroll
                for (int t = 0; t < 2; ++t) {
                    short8 bv = *(const short8*)(wfO + ((size_t)((k * 4 + q) * 2 + t) * 64 + lane) * 8);
                    #pragma unroll
                    for (int pt = 0; pt < 2; ++pt)
                        acc2[pt][t] = __builtin_amdgcn_mfma_f32_16x16x32_bf16(aa[pt], bv, acc2[pt][t], 0, 0, 0);
                }
            }
        }
        if (wave == 1) {
            #pragma unroll
            for (int pt = 0; pt < 2; ++pt)
                #pragma unroll
                for (int t = 0; t < 2; ++t)
                    red[(pt * 2 + t) * 64 + lane] = acc2[pt][t];
        }
        __syncthreads();
        if (wave == 0) {
            #pragma unroll
            for (int pt = 0; pt < 2; ++pt)
                #pragma unroll
                for (int t = 0; t < 2; ++t) {
                    float4v v = acc2[pt][t] + red[(pt * 2 + t) * 64 + lane];
                    int o = 16 * t + col;
                    if (o < 18) {
                        #pragma unroll
                        for (int r = 0; r < 4; ++r)
                            offs[(16 * pt + 4 * s + r) * 18 + o] = v[r];
                    }
                }
        }
        __syncthreads();
    }

    // ================= Phase 2: runtime tap loop, pipelined ====================
    float4v acc[2][8];
    #pragma unroll
    for (int pt = 0; pt < 2; ++pt)
        #pragma unroll
        for (int t = 0; t < 8; ++t) {
            float bv = (wave == 0) ? b_def[16 * t + col] : 0.0f;
            acc[pt][t] = (float4v){bv, bv, bv, bv};
        }

    int    oaddr[2][4];   // [pt][corner] — next tap's gather addresses
    float  wxy[2][4];     // [pt][a0,a1,b0,b1]
    uint4v u[2][8];       // [pt][qq*4 + corner] — in-flight gathers

#define CALC_TAP(K_) do {                                                    \
    int ky = ((K_) * 11) >> 5;                                               \
    int kx = (K_) - 3 * ky;                                                  \
    _Pragma("unroll")                                                        \
    for (int pt = 0; pt < 2; ++pt) {                                         \
        int pxl = 16 * pt + col;                                             \
        int px  = w0 + pxl;                                                  \
        float2 dv = *(const float2*)&offs[pxl * 18 + 2 * (K_)];              \
        float ys = (float)(h - 1 + ky) + dv.x;                               \
        float xs = (float)(px - 1 + kx) + dv.y;                              \
        float y0f = floorf(ys), x0f = floorf(xs);                            \
        float wy = ys - y0f, wx = xs - x0f;                                  \
        int y0 = (int)y0f, x0 = (int)x0f;                                    \
        bool vy0 = (y0 >= 0) && (y0 < Hh);                                   \
        bool vy1 = (y0 + 1 >= 0) && (y0 + 1 < Hh);                           \
        bool vx0 = (x0 >= 0) && (x0 < Ww);                                   \
        bool vx1 = (x0 + 1 >= 0) && (x0 + 1 < Ww);                           \
        int y0c = min(max(y0, 0), Hh - 1), y1c = min(max(y0 + 1, 0), Hh - 1);\
        int x0c = min(max(x0, 0), Ww - 1), x1c = min(max(x0 + 1, 0), Ww - 1);\
        wxy[pt][0] = vx0 ? (1.0f - wx) : 0.0f;                               \
        wxy[pt][1] = vx1 ? wx : 0.0f;                                        \
        wxy[pt][2] = vy0 ? (1.0f - wy) : 0.0f;                               \
        wxy[pt][3] = vy1 ? wy : 0.0f;                                        \
        oaddr[pt][0] = (y0c * Ww + x0c) * Cch + cofs;                        \
        oaddr[pt][1] = (y0c * Ww + x1c) * Cch + cofs;                        \
        oaddr[pt][2] = (y1c * Ww + x0c) * Cch + cofs;                        \
        oaddr[pt][3] = (y1c * Ww + x1c) * Cch + cofs;                        \
    }                                                                        \
} while (0)

#define LOAD_TAP() do {                                                      \
    _Pragma("unroll")                                                        \
    for (int pt = 0; pt < 2; ++pt)                                           \
        _Pragma("unroll")                                                    \
        for (int qq = 0; qq < 2; ++qq)                                       \
            _Pragma("unroll")                                                \
            for (int c4 = 0; c4 < 4; ++c4)                                   \
                u[pt][qq * 4 + c4] =                                         \
                    *(const uint4v*)(xtb + oaddr[pt][c4] + 32 * qq);         \
} while (0)

    CALC_TAP(0);
    LOAD_TAP();

    #pragma unroll 1
    for (int k = 0; k < 9; ++k) {
        // 1. weight prefetch (before next gathers, so MFMA waits don't drain them)
        const unsigned short* wk = wfB + (size_t)k * 16384 + (size_t)(2 * wave) * 4096;
        short8 bva[8], bvb[8];
        #pragma unroll
        for (int t = 0; t < 8; ++t) {
            bva[t] = *(const short8*)(wk + (size_t)t * 512 + (size_t)lane * 8);
            bvb[t] = *(const short8*)(wk + 4096 + (size_t)t * 512 + (size_t)lane * 8);
        }
        // 2. blend this tap (consumes u)
        short8 afr[2][2];
        #pragma unroll
        for (int pt = 0; pt < 2; ++pt) {
            float2v A0 = (float2v){wxy[pt][0], wxy[pt][0]};
            float2v A1 = (float2v){wxy[pt][1], wxy[pt][1]};
            float2v B0 = (float2v){wxy[pt][2], wxy[pt][2]};
            float2v B1 = (float2v){wxy[pt][3], wxy[pt][3]};
            #pragma unroll
            for (int qq = 0; qq < 2; ++qq) {
                uint4v res;
                #pragma unroll
                for (int j = 0; j < 4; ++j) {
                    float2v p00 = up2(u[pt][qq * 4 + 0][j]);
                    float2v p01 = up2(u[pt][qq * 4 + 1][j]);
                    float2v p10 = up2(u[pt][qq * 4 + 2][j]);
                    float2v p11 = up2(u[pt][qq * 4 + 3][j]);
                    float2v t0 = __builtin_elementwise_fma(A1, p01, A0 * p00);
                    float2v t1 = __builtin_elementwise_fma(A1, p11, A0 * p10);
                    float2v rr = __builtin_elementwise_fma(B1, t1, B0 * t0);
                    res[j] = packbf2(rr.x, rr.y);
                }
                afr[pt][qq] = __builtin_bit_cast(short8, res);
            }
        }
        // 3. next tap's addresses + gathers (reuse u; ~full stage lead)
        if (k < 8) {
            CALC_TAP(k + 1);
            LOAD_TAP();
        }
        // 4. MFMAs — weights shared across both pt
        #pragma unroll
        for (int t = 0; t < 8; ++t) {
            acc[0][t] = __builtin_amdgcn_mfma_f32_16x16x32_bf16(afr[0][0], bva[t], acc[0][t], 0, 0, 0);
            acc[1][t] = __builtin_amdgcn_mfma_f32_16x16x32_bf16(afr[1][0], bva[t], acc[1][t], 0, 0, 0);
        }
        #pragma unroll
        for (int t = 0; t < 8; ++t) {
            acc[0][t] = __builtin_amdgcn_mfma_f32_16x16x32_bf16(afr[0][1], bvb[t], acc[0][t], 0, 0, 0);
            acc[1][t] = __builtin_amdgcn_mfma_f32_16x16x32_bf16(afr[1][1], bvb[t], acc[1][t], 0, 0, 0);
        }
    }
#undef CALC_TAP
#undef LOAD_TAP

    // ================= Phase 3: merge + attention epilogue =====================
    if (wave == 1) {
        #pragma unroll
        for (int pt = 0; pt < 2; ++pt)
            #pragma unroll
            for (int t = 0; t < 8; ++t)
                red[(pt * 8 + t) * 64 + lane] = acc[pt][t];
    }
    __syncthreads();
    if (wave == 0) {
        #pragma unroll
        for (int pt = 0; pt < 2; ++pt)
            #pragma unroll
            for (int t = 0; t < 8; ++t)
                acc[pt][t] += red[(pt * 8 + t) * 64 + lane];

        float wA[8];
        #pragma unroll
        for (int t = 0; t < 8; ++t) wA[t] = w_attn[16 * t + col];
        float battn = b_attn[0];
        #pragma unroll
        for (int pt = 0; pt < 2; ++pt) {
            float sig[4];
            #pragma unroll
            for (int r = 0; r < 4; ++r) {
                float pr = 0.0f;
                #pragma unroll
                for (int t = 0; t < 8; ++t) pr = fmaf(acc[pt][t][r], wA[t], pr);
                #pragma unroll
                for (int m = 1; m < 16; m <<= 1) pr += __shfl_xor(pr, m, 64);
                sig[r] = 1.0f / (1.0f + expf(-(pr + battn)));
            }
            #pragma unroll
            for (int t = 0; t < 8; ++t) {
                int o = 16 * t + col;
                #pragma unroll
                for (int r = 0; r < 4; ++r) {
                    int px = w0 + 16 * pt + 4 * s + r;
                    float v = acc[pt][t][r] * sig[r];
                    out[((size_t)(b * Cch + o)) * HW + h * Ww + px] = fmaxf(v, 0.0f);
                }
            }
        }
    }
}

// ---- launch ------------------------------------------------------------------
extern "C" void kernel_launch(void* const* d_in, const int* in_sizes, int n_in,
                              void* d_out, int out_size, void* d_ws, size_t ws_size,
                              hipStream_t stream) {
    const float* x      = (const float*)d_in[0];
    const float* w_off  = (const float*)d_in[1];
    const float* b_off  = (const float*)d_in[2];
    const float* w_def  = (const float*)d_in[3];
    const float* b_def  = (const float*)d_in[4];
    const float* w_attn = (const float*)d_in[5];
    const float* b_attn = (const float*)d_in[6];
    float* out = (float*)d_out;

    char* ws = (char*)d_ws;
    unsigned short* xt  = (unsigned short*)ws;                       // 16,777,216 B
    unsigned short* wfB = (unsigned short*)(ws + 16777216);          //    294,912 B
    unsigned short* wfO = (unsigned short*)(ws + 17072128);          //     73,728 B

    transpose_x_bf16<<<dim3(512, 4, 4), dim3(32, 8), 0, stream>>>(x, xt);
    build_frags<<<720, 256, 0, stream>>>(w_def, w_off, wfB, wfO);
    fused_rt<<<2048, 128, 0, stream>>>(xt, wfB, wfO, b_off, b_def, w_attn, b_attn, out);
}

// Round 13
// 153.542 us; speedup vs baseline: 1.6329x; 1.6329x over previous
//
#include <hip/hip_runtime.h>
#include <math.h>

#define Cch 128
#define Hh 128
#define Ww 128
#define HW (Hh * Ww)

typedef __attribute__((ext_vector_type(8))) short short8;
typedef __attribute__((ext_vector_type(4))) float float4v;
typedef __attribute__((ext_vector_type(2))) float float2v;
typedef __attribute__((ext_vector_type(4))) unsigned int uint4v;

__device__ __forceinline__ unsigned short f2bf(float f) {
    unsigned u = __float_as_uint(f);
    return (unsigned short)((u + 0x8000u) >> 16);
}
__device__ __forceinline__ float2v up2(unsigned u) {
    return (float2v){__uint_as_float(u << 16), __uint_as_float(u & 0xffff0000u)};
}
__device__ __forceinline__ unsigned packbf2(float lo, float hi) {
    unsigned a = __float_as_uint(lo), b = __float_as_uint(hi);
    return ((a + 0x8000u) >> 16) | ((b + 0x8000u) & 0xffff0000u);
}

// ---- K1: x [B][C][H][W] fp32 -> xt [B][HW][C] bf16 ---------------------------
__global__ __launch_bounds__(256) void transpose_x_bf16(const float* __restrict__ x,
                                                        unsigned short* __restrict__ xt) {
    __shared__ float tile[32][33];
    int b  = blockIdx.z;
    int c0 = blockIdx.y * 32;
    int p0 = blockIdx.x * 32;
    int tx = threadIdx.x, ty = threadIdx.y;
    const float* xb = x + (size_t)b * Cch * HW;
    unsigned short* xtb = xt + (size_t)b * HW * Cch;
    #pragma unroll
    for (int i = 0; i < 32; i += 8)
        tile[ty + i][tx] = xb[(size_t)(c0 + ty + i) * HW + p0 + tx];
    __syncthreads();
    #pragma unroll
    for (int i = 0; i < 32; i += 8)
        xtb[(size_t)(p0 + ty + i) * Cch + c0 + tx] = f2bf(tile[tx][ty + i]);
}

// ---- K2: build B-fragment-linear weight layouts (bf16) -----------------------
#define NFB (9 * 4 * 8 * 64 * 8)
#define NFO (9 * 4 * 2 * 64 * 8)
__global__ __launch_bounds__(256) void build_frags(const float* __restrict__ w_def,
                                                   const float* __restrict__ w_off,
                                                   unsigned short* __restrict__ wfB,
                                                   unsigned short* __restrict__ wfO) {
    int idx = blockIdx.x * 256 + threadIdx.x;
    if (idx < NFB) {
        int j = idx & 7, lane = (idx >> 3) & 63, t = (idx >> 9) & 7;
        int q = (idx >> 12) & 3, k = idx >> 14;
        int c = 32 * q + 8 * (lane >> 4) + j;
        int o = 16 * t + (lane & 15);
        wfB[idx] = f2bf(w_def[(size_t)(o * Cch + c) * 9 + k]);
    } else if (idx < NFB + NFO) {
        int i2 = idx - NFB;
        int j = i2 & 7, lane = (i2 >> 3) & 63, t = (i2 >> 9) & 1;
        int q = (i2 >> 10) & 3, k = i2 >> 12;
        int c = 32 * q + 8 * (lane >> 4) + j;
        int o = 16 * t + (lane & 15);
        wfO[i2] = (o < 18) ? f2bf(w_off[(size_t)(o * Cch + c) * 9 + k]) : (unsigned short)0;
    }
}

// ---- block -> (b, h, w0): XCD-pinned (blk%8 = XCD, 2 XCDs per image) ---------
__device__ __forceinline__ void blk_map(int blk, int& b, int& h, int& w0) {
    int xcd = blk & 7;
    b = xcd >> 1;
    int seg = ((xcd & 1) << 8) | (blk >> 3);  // 0..511
    h  = seg >> 2;
    w0 = (seg & 3) << 5;
}

// ---- K3: fully fused, quad-sorted loads + in-wave LDS layout permute ---------
__global__ __launch_bounds__(128, 2) void fused_srt(const unsigned short* __restrict__ xt,
                                                    const unsigned short* __restrict__ wfB,
                                                    const unsigned short* __restrict__ wfO,
                                                    const float* __restrict__ b_off,
                                                    const float* __restrict__ b_def,
                                                    const float* __restrict__ w_attn,
                                                    const float* __restrict__ b_attn,
                                                    float* __restrict__ out) {
    __shared__ float4v red[2 * 8 * 64];   // 16 KiB
    __shared__ float   offs[32 * 18];     // 2.3 KiB
    __shared__ uint4v  smw[2 * 4 * 64];   // 8 KiB: per-wave sorted->frag permute
    int b, h, w0;
    blk_map(blockIdx.x, b, h, w0);
    int tid  = threadIdx.x;
    int wave = tid >> 6;
    int lane = tid & 63;
    int col  = lane & 15;
    int s    = lane >> 4;
    int spx  = lane >> 2;          // sorted: pixel index 0..15
    int sch  = lane & 3;           // sorted: 16-B chunk within 64-B row segment
    int cbase = 64 * wave;
    int csrt  = cbase + sch * 8;   // ushort offset of this lane's chunk
    int wbase = wave * 256;        // smw base (uint4v units)
    int rIdx  = wbase + ((lane & 15) * 4 + (lane >> 4));  // frag-gather source (+buf*64)

    const unsigned short* xtb = xt + (size_t)b * HW * Cch;

    // ================= Phase 1: offset conv (sorted loads + permute) ==========
    {
        float4v acc2[2][2];
        #pragma unroll
        for (int pt = 0; pt < 2; ++pt)
            #pragma unroll
            for (int t = 0; t < 2; ++t) {
                int o = 16 * t + col;
                float bv = (wave == 0 && o < 18) ? b_off[o] : 0.0f;
                acc2[pt][t] = (float4v){bv, bv, bv, bv};
            }

        #pragma unroll
        for (int k = 0; k < 9; ++k) {
            int y = h + (k / 3) - 1;
            bool vy = (y >= 0) && (y < Hh);
            int yc = min(max(y, 0), Hh - 1);
            int dxk = (k % 3) - 1;
            int  ofs[2];
            bool val[2];
            #pragma unroll
            for (int pt = 0; pt < 2; ++pt) {
                int px = w0 + 16 * pt + spx;
                int xs = px + dxk;
                val[pt] = vy && (xs >= 0) && (xs < Ww);
                int xc  = min(max(xs, 0), Ww - 1);
                ofs[pt] = (yc * Ww + xc) * Cch + csrt;
            }
            #pragma unroll
            for (int pt = 0; pt < 2; ++pt)
                #pragma unroll
                for (int qq = 0; qq < 2; ++qq) {
                    uint4v av = *(const uint4v*)(xtb + ofs[pt] + 32 * qq);
                    if (!val[pt]) av = (uint4v){0u, 0u, 0u, 0u};
                    smw[wbase + (pt * 2 + qq) * 64 + lane] = av;
                }
            short8 aa[2][2];
            #pragma unroll
            for (int pt = 0; pt < 2; ++pt)
                #pragma unroll
                for (int qq = 0; qq < 2; ++qq)
                    aa[pt][qq] = __builtin_bit_cast(short8, smw[rIdx + (pt * 2 + qq) * 64]);
            #pragma unroll
            for (int qq = 0; qq < 2; ++qq) {
                int q = 2 * wave + qq;
                #pragma unroll
                for (int t = 0; t < 2; ++t) {
                    short8 bv = *(const short8*)(wfO + ((size_t)((k * 4 + q) * 2 + t) * 64 + lane) * 8);
                    #pragma unroll
                    for (int pt = 0; pt < 2; ++pt)
                        acc2[pt][t] = __builtin_amdgcn_mfma_f32_16x16x32_bf16(aa[pt][qq], bv, acc2[pt][t], 0, 0, 0);
                }
            }
        }
        if (wave == 1) {
            #pragma unroll
            for (int pt = 0; pt < 2; ++pt)
                #pragma unroll
                for (int t = 0; t < 2; ++t)
                    red[(pt * 2 + t) * 64 + lane] = acc2[pt][t];
        }
        __syncthreads();
        if (wave == 0) {
            #pragma unroll
            for (int pt = 0; pt < 2; ++pt)
                #pragma unroll
                for (int t = 0; t < 2; ++t) {
                    float4v v = acc2[pt][t] + red[(pt * 2 + t) * 64 + lane];
                    int o = 16 * t + col;
                    if (o < 18) {
                        #pragma unroll
                        for (int r = 0; r < 4; ++r)
                            offs[(16 * pt + 4 * s + r) * 18 + o] = v[r];
                    }
                }
        }
        __syncthreads();
    }

    // ================= Phase 2: sorted gather pipeline + permute + MFMA =======
    float4v acc[2][8];
    #pragma unroll
    for (int pt = 0; pt < 2; ++pt)
        #pragma unroll
        for (int t = 0; t < 8; ++t) {
            float bv = (wave == 0) ? b_def[16 * t + col] : 0.0f;
            acc[pt][t] = (float4v){bv, bv, bv, bv};
        }

    int    oaddr[2][4];   // [pt][corner]
    float  wxy[2][4];     // [pt][a0,a1,b0,b1]
    uint4v u[2][8];       // [pt][qq*4 + corner]

#define CALC_TAP(K_) do {                                                    \
    int ky = ((K_) * 11) >> 5;                                               \
    int kx = (K_) - 3 * ky;                                                  \
    _Pragma("unroll")                                                        \
    for (int pt = 0; pt < 2; ++pt) {                                         \
        int pxl = 16 * pt + spx;                                             \
        int px  = w0 + pxl;                                                  \
        float2 dv = *(const float2*)&offs[pxl * 18 + 2 * (K_)];              \
        float ys = (float)(h - 1 + ky) + dv.x;                               \
        float xs = (float)(px - 1 + kx) + dv.y;                              \
        float y0f = floorf(ys), x0f = floorf(xs);                            \
        float wy = ys - y0f, wx = xs - x0f;                                  \
        int y0 = (int)y0f, x0 = (int)x0f;                                    \
        bool vy0 = (y0 >= 0) && (y0 < Hh);                                   \
        bool vy1 = (y0 + 1 >= 0) && (y0 + 1 < Hh);                           \
        bool vx0 = (x0 >= 0) && (x0 < Ww);                                   \
        bool vx1 = (x0 + 1 >= 0) && (x0 + 1 < Ww);                           \
        int y0c = min(max(y0, 0), Hh - 1), y1c = min(max(y0 + 1, 0), Hh - 1);\
        int x0c = min(max(x0, 0), Ww - 1), x1c = min(max(x0 + 1, 0), Ww - 1);\
        wxy[pt][0] = vx0 ? (1.0f - wx) : 0.0f;                               \
        wxy[pt][1] = vx1 ? wx : 0.0f;                                        \
        wxy[pt][2] = vy0 ? (1.0f - wy) : 0.0f;                               \
        wxy[pt][3] = vy1 ? wy : 0.0f;                                        \
        oaddr[pt][0] = (y0c * Ww + x0c) * Cch + csrt;                        \
        oaddr[pt][1] = (y0c * Ww + x1c) * Cch + csrt;                        \
        oaddr[pt][2] = (y1c * Ww + x0c) * Cch + csrt;                        \
        oaddr[pt][3] = (y1c * Ww + x1c) * Cch + csrt;                        \
    }                                                                        \
} while (0)

#define LOAD_TAP() do {                                                      \
    _Pragma("unroll")                                                        \
    for (int pt = 0; pt < 2; ++pt)                                           \
        _Pragma("unroll")                                                    \
        for (int qq = 0; qq < 2; ++qq)                                       \
            _Pragma("unroll")                                                \
            for (int c4 = 0; c4 < 4; ++c4)                                   \
                u[pt][qq * 4 + c4] =                                         \
                    *(const uint4v*)(xtb + oaddr[pt][c4] + 32 * qq);         \
} while (0)

    CALC_TAP(0);
    LOAD_TAP();

    #pragma unroll
    for (int k = 0; k < 9; ++k) {
        // 1. weight prefetch
        const unsigned short* wk = wfB + (size_t)k * 16384 + (size_t)(2 * wave) * 4096;
        short8 bva[8], bvb[8];
        #pragma unroll
        for (int t = 0; t < 8; ++t) {
            bva[t] = *(const short8*)(wk + (size_t)t * 512 + (size_t)lane * 8);
            bvb[t] = *(const short8*)(wk + 4096 + (size_t)t * 512 + (size_t)lane * 8);
        }
        // 2. blend (sorted layout, lane-local) + permute-write
        #pragma unroll
        for (int pt = 0; pt < 2; ++pt) {
            float2v A0 = (float2v){wxy[pt][0], wxy[pt][0]};
            float2v A1 = (float2v){wxy[pt][1], wxy[pt][1]};
            float2v B0 = (float2v){wxy[pt][2], wxy[pt][2]};
            float2v B1 = (float2v){wxy[pt][3], wxy[pt][3]};
            #pragma unroll
            for (int qq = 0; qq < 2; ++qq) {
                uint4v res;
                #pragma unroll
                for (int j = 0; j < 4; ++j) {
                    float2v p00 = up2(u[pt][qq * 4 + 0][j]);
                    float2v p01 = up2(u[pt][qq * 4 + 1][j]);
                    float2v p10 = up2(u[pt][qq * 4 + 2][j]);
                    float2v p11 = up2(u[pt][qq * 4 + 3][j]);
                    float2v t0 = __builtin_elementwise_fma(A1, p01, A0 * p00);
                    float2v t1 = __builtin_elementwise_fma(A1, p11, A0 * p10);
                    float2v rr = __builtin_elementwise_fma(B1, t1, B0 * t0);
                    res[j] = packbf2(rr.x, rr.y);
                }
                smw[wbase + (pt * 2 + qq) * 64 + lane] = res;
            }
        }
        // 3. next tap's addresses + gathers (reuse u)
        if (k < 8) {
            CALC_TAP(k + 1);
            LOAD_TAP();
        }
        // 4. permute-read into fragment layout, then MFMAs (shared weights)
        short8 afr[2][2];
        #pragma unroll
        for (int pt = 0; pt < 2; ++pt)
            #pragma unroll
            for (int qq = 0; qq < 2; ++qq)
                afr[pt][qq] = __builtin_bit_cast(short8, smw[rIdx + (pt * 2 + qq) * 64]);
        #pragma unroll
        for (int t = 0; t < 8; ++t) {
            acc[0][t] = __builtin_amdgcn_mfma_f32_16x16x32_bf16(afr[0][0], bva[t], acc[0][t], 0, 0, 0);
            acc[1][t] = __builtin_amdgcn_mfma_f32_16x16x32_bf16(afr[1][0], bva[t], acc[1][t], 0, 0, 0);
        }
        #pragma unroll
        for (int t = 0; t < 8; ++t) {
            acc[0][t] = __builtin_amdgcn_mfma_f32_16x16x32_bf16(afr[0][1], bvb[t], acc[0][t], 0, 0, 0);
            acc[1][t] = __builtin_amdgcn_mfma_f32_16x16x32_bf16(afr[1][1], bvb[t], acc[1][t], 0, 0, 0);
        }
    }
#undef CALC_TAP
#undef LOAD_TAP

    // ================= Phase 3: merge + attention epilogue =====================
    if (wave == 1) {
        #pragma unroll
        for (int pt = 0; pt < 2; ++pt)
            #pragma unroll
            for (int t = 0; t < 8; ++t)
                red[(pt * 8 + t) * 64 + lane] = acc[pt][t];
    }
    __syncthreads();
    if (wave == 0) {
        #pragma unroll
        for (int pt = 0; pt < 2; ++pt)
            #pragma unroll
            for (int t = 0; t < 8; ++t)
                acc[pt][t] += red[(pt * 8 + t) * 64 + lane];

        float wA[8];
        #pragma unroll
        for (int t = 0; t < 8; ++t) wA[t] = w_attn[16 * t + col];
        float battn = b_attn[0];
        #pragma unroll
        for (int pt = 0; pt < 2; ++pt) {
            float sig[4];
            #pragma unroll
            for (int r = 0; r < 4; ++r) {
                float pr = 0.0f;
                #pragma unroll
                for (int t = 0; t < 8; ++t) pr = fmaf(acc[pt][t][r], wA[t], pr);
                #pragma unroll
                for (int m = 1; m < 16; m <<= 1) pr += __shfl_xor(pr, m, 64);
                sig[r] = 1.0f / (1.0f + expf(-(pr + battn)));
            }
            #pragma unroll
            for (int t = 0; t < 8; ++t) {
                int o = 16 * t + col;
                #pragma unroll
                for (int r = 0; r < 4; ++r) {
                    int px = w0 + 16 * pt + 4 * s + r;
                    float v = acc[pt][t][r] * sig[r];
                    out[((size_t)(b * Cch + o)) * HW + h * Ww + px] = fmaxf(v, 0.0f);
                }
            }
        }
    }
}

// ---- launch ------------------------------------------------------------------
extern "C" void kernel_launch(void* const* d_in, const int* in_sizes, int n_in,
                              void* d_out, int out_size, void* d_ws, size_t ws_size,
                              hipStream_t stream) {
    const float* x      = (const float*)d_in[0];
    const float* w_off  = (const float*)d_in[1];
    const float* b_off  = (const float*)d_in[2];
    const float* w_def  = (const float*)d_in[3];
    const float* b_def  = (const float*)d_in[4];
    const float* w_attn = (const float*)d_in[5];
    const float* b_attn = (const float*)d_in[6];
    float* out = (float*)d_out;

    char* ws = (char*)d_ws;
    unsigned short* xt  = (unsigned short*)ws;                       // 16,777,216 B
    unsigned short* wfB = (unsigned short*)(ws + 16777216);          //    294,912 B
    unsigned short* wfO = (unsigned short*)(ws + 17072128);          //     73,728 B

    transpose_x_bf16<<<dim3(512, 4, 4), dim3(32, 8), 0, stream>>>(x, xt);
    build_frags<<<720, 256, 0, stream>>>(w_def, w_off, wfB, wfO);
    fused_srt<<<2048, 128, 0, stream>>>(xt, wfB, wfO, b_off, b_def, w_attn, b_attn, out);
}